// Round 6
// baseline (358.475 us; speedup 1.0000x reference)
//
#include <hip/hip_runtime.h>
#include <math.h>

// Problem constants (fixed by setup_inputs)
#define BN    4096
#define DD    1024
#define CC    1000
#define MM    32768
#define ROWS_CAP 32768   // worst-case B + mem_ptr
#define SIMLD 1024       // sim row stride (bf16 elements)
#define CNT_BLKS 256     // count-partial blocks (64 row-groups x 4 class-quarters)

typedef __attribute__((ext_vector_type(8))) int   int8v;
typedef __attribute__((ext_vector_type(16))) float f32x16;

__device__ __forceinline__ float wave_max_f(float v) {
#pragma unroll
  for (int off = 32; off >= 1; off >>= 1) v = fmaxf(v, __shfl_xor(v, off, 64));
  return v;
}
__device__ __forceinline__ float wave_sum_f(float v) {
#pragma unroll
  for (int off = 32; off >= 1; off >>= 1) v += __shfl_xor(v, off, 64);
  return v;
}

// round-to-nearest-even float -> bf16 bits (finite inputs)
__device__ __forceinline__ short f2bf(float f) {
  union { float f; unsigned u; } v; v.f = f;
  unsigned r = v.u + 0x7FFF + ((v.u >> 16) & 1);
  return (short)(r >> 16);
}
__device__ __forceinline__ float bf2f(unsigned short u) {
  union { unsigned u; float f; } v; v.u = ((unsigned)u) << 16;
  return v.f;
}

__device__ __forceinline__ void gload16(const unsigned char* g, unsigned char* l) {
  __builtin_amdgcn_global_load_lds(
      (const __attribute__((address_space(1))) unsigned int*)g,
      (__attribute__((address_space(3))) unsigned int*)l, 16, 0, 0);
}

// ---------------------------------------------------------------- prep über-kernel
// blocks [0, ROWS_CAP): enhanced row -> A fp8 (image rows normalized, mem raw)
// blocks [ROWS_CAP, ROWS_CAP+1024): prompt row -> B fp8 (10*invnorm folded, pad 0)
// blocks [ROWS_CAP+1024, +CNT_BLKS): label count partials (non-atomic)
__global__ __launch_bounds__(256) void prep_kernel(const float* __restrict__ img,
                                                   const float* __restrict__ prompts,
                                                   const float* __restrict__ mem,
                                                   const int* __restrict__ labels,
                                                   const int* __restrict__ memptr,
                                                   unsigned char* __restrict__ A,
                                                   unsigned char* __restrict__ B,
                                                   int* __restrict__ counts_part) {
  __shared__ float part[4];
  const int t = threadIdx.x;
  const int blk = blockIdx.x;

  if (blk >= ROWS_CAP + 1024) {                       // ---- count partials
    const int cb = blk - (ROWS_CAP + 1024);
    const int g = cb >> 2;                            // row group 0..63
    const int c = (cb & 3) * 256 + t;
    if (c >= CC) return;
    const int b0 = g * 64;
    int s = 0;
    for (int b = b0; b < b0 + 64; ++b) s += labels[(size_t)b * CC + c];
    counts_part[g * CC + c] = s;
    return;
  }

  if (blk >= ROWS_CAP) {                              // ---- B conversion
    const int row = blk - ROWS_CAP;
    int packed = 0;
    if (row < CC) {
      float4 v = ((const float4*)(prompts + (size_t)row * DD))[t];
      float s = v.x * v.x + v.y * v.y + v.z * v.z + v.w * v.w;
      s = wave_sum_f(s);
      if ((t & 63) == 0) part[t >> 6] = s;
      __syncthreads();
      float sc = 10.0f * rsqrtf(part[0] + part[1] + part[2] + part[3] + 1e-24f);
      packed = __builtin_amdgcn_cvt_pk_fp8_f32(v.x * sc, v.y * sc, 0, false);
      packed = __builtin_amdgcn_cvt_pk_fp8_f32(v.z * sc, v.w * sc, packed, true);
    }
    ((int*)(B + (size_t)row * DD))[t] = packed;
    return;
  }

  // ---- A conversion
  const int nrows = BN + memptr[0];
  const int padded = (nrows + 127) & ~127;
  const int row = blk;
  if (row >= padded) return;
  int packed = 0;
  if (row < nrows) {
    const float* src = (row < BN) ? img + (size_t)row * DD
                                  : mem + (size_t)(row - BN) * DD;
    float4 v = ((const float4*)src)[t];
    float sc = 1.0f;
    if (row < BN) {
      float s = v.x * v.x + v.y * v.y + v.z * v.z + v.w * v.w;
      s = wave_sum_f(s);
      if ((t & 63) == 0) part[t >> 6] = s;
      __syncthreads();
      sc = rsqrtf(part[0] + part[1] + part[2] + part[3] + 1e-24f);
    }
    packed = __builtin_amdgcn_cvt_pk_fp8_f32(v.x * sc, v.y * sc, 0, false);
    packed = __builtin_amdgcn_cvt_pk_fp8_f32(v.z * sc, v.w * sc, packed, true);
  }
  ((int*)(A + (size_t)row * DD))[t] = packed;
}

// ---------------------------------------------------------------- class weights
__global__ __launch_bounds__(1024) void weights_kernel(const int* __restrict__ counts_part,
                                                       float* __restrict__ weights) {
  const int t = threadIdx.x;
  float w = 0.f;
  if (t < CC) {
    int cnt = 0;
#pragma unroll 8
    for (int g = 0; g < 64; ++g) cnt += counts_part[g * CC + t];
    float en = 1.0f - expf((float)cnt * logf(0.999f));   // 1 - BETA^cnt
    w = (1.0f - 0.999f) / (en + 1e-8f);
  }
  float s = wave_sum_f(w);
  __shared__ float part[16];
  if ((t & 63) == 0) part[t >> 6] = s;
  __syncthreads();
  float tot = 0.f;
#pragma unroll
  for (int i = 0; i < 16; ++i) tot += part[i];
  if (t < CC) weights[t] = w * ((float)CC / tot);
}

// ---------------------------------------------------------------- MX-fp8 MFMA GEMM
// 128x128 tile, BK=128 bytes, chunk-major LDS (phys = kc*2048 + r*16),
// mfma_scale_f32_32x32x64_f8f6f4 with unit scales; XCD-affine block remap.
__global__ __launch_bounds__(256) void gemm_mx(const unsigned char* __restrict__ A,
                                               const unsigned char* __restrict__ Bm,
                                               const int* __restrict__ memptr,
                                               short* __restrict__ simbf, int lo) {
  const int f = blockIdx.x;
  const int x = f & 7;
  const int s = f >> 3;
  const int c = s & 7;
  const int rt = (s >> 3) * 8 + x;

  const int nrows = BN + memptr[0];
  const int row0 = rt * 128;                 // local row within chunk
  if (lo + row0 >= nrows) return;
  const int c0 = c * 128;

  __shared__ unsigned char As[16384];
  __shared__ unsigned char Bs[16384];

  const int t = threadIdx.x;
  const int lane = t & 63;
  const int wid = t >> 6;
  const int wm = (wid >> 1) * 64;
  const int wn = (wid & 1) * 64;

  // stager: slot s = p*256 + t -> kc = slot>>7 (16B k-chunk), r = slot&127
  const int r_st = t & 127;
  const int kc_hi = t >> 7;                  // 0..1
  const unsigned char* gaB = A + (size_t)(lo + row0 + r_st) * DD;
  const unsigned char* gbB = Bm + (size_t)(c0 + r_st) * DD;
  unsigned char* lA = As + t * 16;
  unsigned char* lB = Bs + t * 16;

  f32x16 acc[2][2] = {};
  const int q = lane >> 5;                   // k-half-of-32 selector
  const int rr = lane & 31;

  for (int k0 = 0; k0 < DD; k0 += 128) {
#pragma unroll
    for (int p = 0; p < 4; ++p)
      gload16(gaB + k0 + (p * 2 + kc_hi) * 16, lA + p * 4096);
#pragma unroll
    for (int p = 0; p < 4; ++p)
      gload16(gbB + k0 + (p * 2 + kc_hi) * 16, lB + p * 4096);
    __syncthreads();
#pragma unroll
    for (int h = 0; h < 2; ++h) {
      int8v af[2], bfv[2];
      const int kc = h * 4 + q * 2;
#pragma unroll
      for (int mi = 0; mi < 2; ++mi) {
        const unsigned char* pa = As + kc * 2048 + (wm + mi * 32 + rr) * 16;
        int4 lo4 = *(const int4*)pa;
        int4 hi4 = *(const int4*)(pa + 2048);
        af[mi][0] = lo4.x; af[mi][1] = lo4.y; af[mi][2] = lo4.z; af[mi][3] = lo4.w;
        af[mi][4] = hi4.x; af[mi][5] = hi4.y; af[mi][6] = hi4.z; af[mi][7] = hi4.w;
      }
#pragma unroll
      for (int ni = 0; ni < 2; ++ni) {
        const unsigned char* pb = Bs + kc * 2048 + (wn + ni * 32 + rr) * 16;
        int4 lo4 = *(const int4*)pb;
        int4 hi4 = *(const int4*)(pb + 2048);
        bfv[ni][0] = lo4.x; bfv[ni][1] = lo4.y; bfv[ni][2] = lo4.z; bfv[ni][3] = lo4.w;
        bfv[ni][4] = hi4.x; bfv[ni][5] = hi4.y; bfv[ni][6] = hi4.z; bfv[ni][7] = hi4.w;
      }
#pragma unroll
      for (int mi = 0; mi < 2; ++mi)
#pragma unroll
        for (int ni = 0; ni < 2; ++ni)
          acc[mi][ni] = __builtin_amdgcn_mfma_scale_f32_32x32x64_f8f6f4(
              af[mi], bfv[ni], acc[mi][ni], 0, 0, 0, 127, 0, 127);
    }
    __syncthreads();
  }

  // C/D layout (32x32): col = lane&31, row = (reg&3) + 8*(reg>>2) + 4*(lane>>5)
  const int cl = lane & 31;
  const int r4 = 4 * (lane >> 5);
#pragma unroll
  for (int mi = 0; mi < 2; ++mi)
#pragma unroll
    for (int ni = 0; ni < 2; ++ni) {
      f32x16 v = acc[mi][ni];
      const int colg = c0 + wn + ni * 32 + cl;
      const int rbase = row0 + wm + mi * 32 + r4;
#pragma unroll
      for (int reg = 0; reg < 16; ++reg) {
        const int rowl = rbase + (reg & 3) + 8 * (reg >> 2);
        simbf[(size_t)rowl * SIMLD + colg] = f2bf(v[reg]);
      }
    }
}

// ---------------------------------------------------------------- per-row epilogue
// One wave per row; block reduces its 4 rows -> one partial pair per block.
__global__ __launch_bounds__(256) void rowpost_kernel(
    const short* __restrict__ simbf, const int* __restrict__ labels,
    const int* __restrict__ mlabels, const float* __restrict__ weights,
    const int* __restrict__ memptr, float* __restrict__ part_l,
    float* __restrict__ part_v, int chunk_lo) {
  const int nrows = BN + memptr[0];
  const int blk = blockIdx.x;
  const int row0 = chunk_lo + blk * 4;
  const int pslot = chunk_lo / 4 + blk;
  if (row0 >= nrows) {
    if (threadIdx.x == 0) { part_l[pslot] = 0.f; part_v[pslot] = 0.f; }
    return;
  }

  __shared__ float wlds[1024];
  {
    const int t = threadIdx.x;
#pragma unroll
    for (int i = 0; i < 4; ++i) {
      int c = t + i * 256;
      wlds[c] = (c < CC) ? weights[c] : 0.f;
    }
  }
  __syncthreads();

  const int wid = threadIdx.x >> 6;
  const int lane = threadIdx.x & 63;
  const int row = row0 + wid;
  float c_l = 0.f, c_v = 0.f;

  if (row < nrows) {
    const unsigned short* srow = (const unsigned short*)simbf + (size_t)(row - chunk_lo) * SIMLD;
    const int* lrow = (row < BN) ? labels + (size_t)row * CC
                                 : mlabels + (size_t)(row - BN) * CC;
    const int cbase = lane * 16;

    unsigned short sraw[16];
    *(ulonglong2*)&sraw[0] = *(const ulonglong2*)(srow + cbase);
    *(ulonglong2*)&sraw[8] = *(const ulonglong2*)(srow + cbase + 8);
    int lab[16];
#pragma unroll
    for (int g = 0; g < 4; ++g) {
      int c = cbase + g * 4;
      if (c + 3 < CC) {
        *(int4*)&lab[g * 4] = *(const int4*)(lrow + c);
      } else {
#pragma unroll
        for (int u = 0; u < 4; ++u) lab[g * 4 + u] = (c + u < CC) ? lrow[c + u] : 0;
      }
    }

    float sv[16];
    bool pv[16];
    float vneg[16];
#pragma unroll
    for (int j = 0; j < 16; ++j) {
      int c = cbase + j;
      bool ok = (c < CC);
      float sf = bf2f(sraw[j]);
      bool p = ok && (lab[j] > 0);
      sv[j] = ok ? sf : -INFINITY;
      pv[j] = p;
      vneg[j] = (ok && !p) ? sf : -INFINITY;
    }

    // 10 rounds of max-extraction over negatives -> 10th largest negative
    float v10 = -INFINITY;
    for (int r = 0; r < 10; ++r) {
      float lmx = -INFINITY;
#pragma unroll
      for (int j = 0; j < 16; ++j) lmx = fmaxf(lmx, vneg[j]);
      lmx = wave_max_f(lmx);
#pragma unroll
      for (int j = 0; j < 16; ++j) if (vneg[j] == lmx) vneg[j] = -INFINITY;
      v10 = lmx;
    }

    // masked LSE + weighted sums
    float mmax = -INFINITY;
#pragma unroll
    for (int j = 0; j < 16; ++j) {
      if (pv[j] || sv[j] >= v10) mmax = fmaxf(mmax, sv[j]);
    }
    mmax = wave_max_f(mmax);

    float esum = 0.f, wsum = 0.f, wsim = 0.f;
#pragma unroll
    for (int j = 0; j < 16; ++j) {
      int c = cbase + j;
      if (c < CC) {
        if (pv[j] || sv[j] >= v10) esum += expf(sv[j] - mmax);
        if (pv[j]) { float w = wlds[c]; wsum += w; wsim += w * sv[j]; }
      }
    }
    esum = wave_sum_f(esum);
    wsum = wave_sum_f(wsum);
    wsim = wave_sum_f(wsim);

    if (lane == 0) {
      float lse = mmax + logf(esum);
      bool valid = (wsum > 0.f);
      float lps = valid ? (wsum * lse - wsim) / (wsum + 1e-8f) : 0.f;
      float mult = (row < BN) ? 2.f : 1.f;   // image rows appear twice in enhanced set
      c_l = mult * lps;
      c_v = valid ? mult : 0.f;
    }
  }

  __shared__ float bl[4], bv[4];
  if (lane == 0) { bl[wid] = c_l; bv[wid] = c_v; }
  __syncthreads();
  if (threadIdx.x == 0) {
    part_l[pslot] = bl[0] + bl[1] + bl[2] + bl[3];
    part_v[pslot] = bv[0] + bv[1] + bv[2] + bv[3];
  }
}

// ---------------------------------------------------------------- finalize
__global__ __launch_bounds__(1024) void finalize_kernel(const float* __restrict__ part_l,
                                                        const float* __restrict__ part_v,
                                                        float* __restrict__ out) {
  const int t = threadIdx.x;
  const float4* l4 = (const float4*)part_l;
  const float4* v4 = (const float4*)part_v;
  float s1 = 0.f, s2 = 0.f;
#pragma unroll
  for (int i = 0; i < 2; ++i) {
    float4 a = l4[t + i * 1024];
    float4 b = v4[t + i * 1024];
    s1 += a.x + a.y + a.z + a.w;
    s2 += b.x + b.y + b.z + b.w;
  }
  s1 = wave_sum_f(s1);
  s2 = wave_sum_f(s2);
  __shared__ float p1[16], p2[16];
  if ((t & 63) == 0) { p1[t >> 6] = s1; p2[t >> 6] = s2; }
  __syncthreads();
  if (t == 0) {
    float a = 0.f, b = 0.f;
#pragma unroll
    for (int i = 0; i < 16; ++i) { a += p1[i]; b += p2[i]; }
    out[0] = a / fmaxf(b, 1.0f);
  }
}

// ---------------------------------------------------------------- launcher
extern "C" void kernel_launch(void* const* d_in, const int* in_sizes, int n_in,
                              void* d_out, int out_size, void* d_ws, size_t ws_size,
                              hipStream_t stream) {
  const float* img     = (const float*)d_in[0];
  const float* prompts = (const float*)d_in[1];
  const int*   labels  = (const int*)d_in[2];
  const float* mem     = (const float*)d_in[3];
  const int*   mlabels = (const int*)d_in[4];
  const int*   memptr  = (const int*)d_in[5];
  float* out = (float*)d_out;
  char* ws = (char*)d_ws;

  int*   counts_part = (int*)(ws + 4096);           // 64 x 1000 ints = 256000 B
  float* weights     = (float*)(ws + 262144);       // 1000 f
  float* part_l      = (float*)(ws + 266240);       // 8192 f = 32 KiB
  float* part_v      = (float*)(ws + 299008);       // 8192 f = 32 KiB
  unsigned char* Bf8 = (unsigned char*)(ws + 335872);    // 1024x1024 fp8 = 1 MiB
  unsigned char* Af8 = (unsigned char*)(ws + 1384448);   // 32768x1024 fp8 = 32 MiB
  const size_t fixed = 1384448 + (size_t)ROWS_CAP * DD;  // 34938880
  short* simbf = (short*)(ws + fixed);

  // sim chunk rows (multiple of 1024 so row-tiles per chunk are a multiple of 8)
  long long avail = (long long)ws_size - (long long)fixed;
  int chunk = (int)(avail / (SIMLD * 2));
  chunk &= ~1023;
  if (chunk < 1024) chunk = 1024;
  if (chunk > ROWS_CAP) chunk = ROWS_CAP;

  prep_kernel<<<ROWS_CAP + 1024 + CNT_BLKS, 256, 0, stream>>>(
      img, prompts, mem, labels, memptr, Af8, Bf8, counts_part);
  weights_kernel<<<1, 1024, 0, stream>>>(counts_part, weights);

  for (int lo = 0; lo < ROWS_CAP; lo += chunk) {
    int rows = (ROWS_CAP - lo < chunk) ? (ROWS_CAP - lo) : chunk;
    int rowTiles = rows / 128;              // multiple of 8
    gemm_mx<<<8 * rowTiles, 256, 0, stream>>>(Af8, Bf8, memptr, simbf, lo);
    rowpost_kernel<<<rows / 4, 256, 0, stream>>>(simbf, labels, mlabels, weights, memptr,
                                                 part_l, part_v, lo);
  }
  finalize_kernel<<<1, 1024, 0, stream>>>(part_l, part_v, out);
}